// Round 9
// baseline (626.371 us; speedup 1.0000x reference)
//
#include <hip/hip_runtime.h>
#include <math.h>

#define NN 100000
#define EE 1600000
#define GG 64
#define DD 64
#define NF 128
#define EF 32
#define LVL 3
#define EPSBN 1e-5f
#define NTILES ((NN + 63) / 64)
#define NBKT 391  // ceil(NN / 256)

typedef unsigned short u16;
typedef unsigned int u32;
typedef unsigned long long u64;
typedef short s4v __attribute__((ext_vector_type(4)));
typedef short bf16x8 __attribute__((ext_vector_type(8)));
typedef float f32x4 __attribute__((ext_vector_type(4)));

__device__ __forceinline__ float4 ld4(const float* p) { return *(const float4*)p; }
__device__ __forceinline__ u16 f2b(float f) {
    u32 u = __float_as_uint(f);
    return (u16)((u + 0x7FFFu + ((u >> 16) & 1u)) >> 16);
}
__device__ __forceinline__ u32 pk2(float x, float y) {
    return (u32)f2b(x) | ((u32)f2b(y) << 16);
}
__device__ __forceinline__ float b2f(u16 u) { return __uint_as_float(((u32)u) << 16); }
__device__ __forceinline__ float blo(u32 u) { return __uint_as_float(u << 16); }
__device__ __forceinline__ float bhi(u32 u) { return __uint_as_float(u & 0xFFFF0000u); }

// BN scale/shift from raw sums slot (training-mode biased stats)
__device__ __forceinline__ float2 bn_pair(const float* __restrict__ slot,
                                          const float* __restrict__ g,
                                          const float* __restrict__ b, int ch) {
    float mean = slot[ch] * (1.0f / NN);
    float var = slot[64 + ch] * (1.0f / NN) - mean * mean;
    float sc = g[ch] * rsqrtf(fmaxf(var, 0.f) + EPSBN);
    return make_float2(sc, b[ch] - mean * sc);
}

// ---------------- CSR build: two-level bucket sort ----------------
__global__ void k1b(const int* __restrict__ to, int* __restrict__ bhist) {
    __shared__ int h[NBKT];
    for (int i = threadIdx.x; i < NBKT; i += 256) h[i] = 0;
    __syncthreads();
    for (int e = blockIdx.x * 256 + threadIdx.x; e < EE; e += 256 * gridDim.x)
        atomicAdd(&h[to[e] >> 8], 1);
    __syncthreads();
    for (int i = threadIdx.x; i < NBKT; i += 256)
        if (h[i]) atomicAdd(&bhist[i], h[i]);
}

__global__ void k1c(const int* __restrict__ bhist, int* __restrict__ bbase,
                    int* __restrict__ gcur) {
    __shared__ int s[512];
    int t = threadIdx.x;
    s[t] = (t < NBKT) ? bhist[t] : 0;
    __syncthreads();
    for (int off = 1; off < 512; off <<= 1) {
        int v = (t >= off) ? s[t - off] : 0;
        __syncthreads();
        s[t] += v;
        __syncthreads();
    }
    if (t < NBKT) {
        int base = t ? s[t - 1] : 0;
        bbase[t] = base;
        gcur[t] = base;
    }
    if (t == NBKT - 1) bbase[NBKT] = s[t];
}

// partition edges into bucket-contiguous order, carrying the bf16 ef payload
// tmpw[pos] = from | (rel_to<<17);  tmp_ef[pos] = ef row (32ch bf16 = 64B)
__global__ void k1d(const int* __restrict__ to, const int* __restrict__ from,
                    const float* __restrict__ ef, int* __restrict__ gcur,
                    int* __restrict__ tmpw, uint4* __restrict__ tmp_ef) {
    __shared__ int h[NBKT];
    __shared__ int cur[NBKT];
    for (int i = threadIdx.x; i < NBKT; i += 256) h[i] = 0;
    __syncthreads();
    for (int e = blockIdx.x * 256 + threadIdx.x; e < EE; e += 256 * gridDim.x)
        atomicAdd(&h[to[e] >> 8], 1);
    __syncthreads();
    for (int i = threadIdx.x; i < NBKT; i += 256)
        cur[i] = h[i] ? atomicAdd(&gcur[i], h[i]) : 0;
    __syncthreads();
    for (int e = blockIdx.x * 256 + threadIdx.x; e < EE; e += 256 * gridDim.x) {
        int tt = to[e];
        int b = tt >> 8;
        int pos = atomicAdd(&cur[b], 1);
        tmpw[pos] = from[e] | ((tt & 255) << 17);
        const float4* efp = (const float4*)(ef + (size_t)e * EF);
        uint4* dst = tmp_ef + (size_t)pos * 4;
#pragma unroll
        for (int j = 0; j < 4; j++) {
            float4 a = efp[2 * j], b4 = efp[2 * j + 1];
            dst[j] = make_uint4(pk2(a.x, a.y), pk2(a.z, a.w), pk2(b4.x, b4.y),
                                pk2(b4.z, b4.w));
        }
    }
}

// per-bucket: histogram+scan -> row_ptr; scatter src/perm; per-node payload sum -> pooled
__global__ void kp2(const int* __restrict__ tmpw, const uint4* __restrict__ tmp_ef,
                    const int* __restrict__ bbase, int* __restrict__ row_ptr,
                    int* __restrict__ src_s, int* __restrict__ perm,
                    u16* __restrict__ pooled) {
    __shared__ int s[256];
    __shared__ int cur[256];
    int b = blockIdx.x, t = threadIdx.x;
    int e0 = bbase[b], e1 = bbase[b + 1];
    s[t] = 0;
    __syncthreads();
    for (int e = e0 + t; e < e1; e += 256) atomicAdd(&s[(tmpw[e] >> 17) & 255], 1);
    __syncthreads();
    int v = s[t];
    for (int off = 1; off < 256; off <<= 1) {
        int u = (t >= off) ? s[t - off] : 0;
        __syncthreads();
        s[t] += u;
        __syncthreads();
    }
    int excl = e0 + s[t] - v;
    cur[t] = excl;
    int n = b * 256 + t;
    if (n < NN) row_ptr[n] = excl;
    if (b == NBKT - 1 && t == 0) row_ptr[NN] = e1;
    __syncthreads();
    for (int e = e0 + t; e < e1; e += 256) {
        int w = tmpw[e];
        int pos = atomicAdd(&cur[(w >> 17) & 255], 1);
        src_s[pos] = w & 0x1FFFF;
        perm[pos] = e;
    }
    __threadfence_block();
    __syncthreads();
    // per-node: gather payloads via perm (bucket-local, L2-hot), sum in registers
    if (n < NN) {
        float av[EF];
#pragma unroll
        for (int c = 0; c < EF; c++) av[c] = 0.f;
        for (int i = 0; i < v; i++) {
            int e = perm[excl + i];
            const uint4* p = tmp_ef + (size_t)e * 4;
            uint4 q0 = p[0], q1 = p[1], q2 = p[2], q3 = p[3];
            av[0] += blo(q0.x); av[1] += bhi(q0.x); av[2] += blo(q0.y); av[3] += bhi(q0.y);
            av[4] += blo(q0.z); av[5] += bhi(q0.z); av[6] += blo(q0.w); av[7] += bhi(q0.w);
            av[8] += blo(q1.x); av[9] += bhi(q1.x); av[10] += blo(q1.y); av[11] += bhi(q1.y);
            av[12] += blo(q1.z); av[13] += bhi(q1.z); av[14] += blo(q1.w); av[15] += bhi(q1.w);
            av[16] += blo(q2.x); av[17] += bhi(q2.x); av[18] += blo(q2.y); av[19] += bhi(q2.y);
            av[20] += blo(q2.z); av[21] += bhi(q2.z); av[22] += blo(q2.w); av[23] += bhi(q2.w);
            av[24] += blo(q3.x); av[25] += bhi(q3.x); av[26] += blo(q3.y); av[27] += bhi(q3.y);
            av[28] += blo(q3.z); av[29] += bhi(q3.z); av[30] += blo(q3.w); av[31] += bhi(q3.w);
        }
        u32 orow[16];
#pragma unroll
        for (int j = 0; j < 16; j++) orow[j] = pk2(av[2 * j], av[2 * j + 1]);
        uint4* pr = (uint4*)((u32*)pooled + (size_t)n * 16);
        pr[0] = make_uint4(orow[0], orow[1], orow[2], orow[3]);
        pr[1] = make_uint4(orow[4], orow[5], orow[6], orow[7]);
        pr[2] = make_uint4(orow[8], orow[9], orow[10], orow[11]);
        pr[3] = make_uint4(orow[12], orow[13], orow[14], orow[15]);
    }
}

// ---------------- MFMA bf16 fused GEMM (h0 / merge / l2), inline BN ----------------
template <int K1, int K2, bool A1BF, bool AAFF, bool EMB, bool BE, bool RESID>
__global__ __launch_bounds__(256) void kgemm_mfma(
    const void* __restrict__ A1v, const u16* __restrict__ A2,
    const float* __restrict__ W1, const float* __restrict__ W2,
    const float* __restrict__ bias, const float* __restrict__ be,
    const int* __restrict__ row_ptr, const float* __restrict__ emb,
    const int* __restrict__ nvi, const u16* __restrict__ resid,
    const float* __restrict__ rslot, const float* __restrict__ rg,
    const float* __restrict__ rb, const float* __restrict__ aslot,
    const float* __restrict__ ag, const float* __restrict__ ab,
    u16* __restrict__ Xb, float* __restrict__ stats) {
    constexpr int K = K1 + K2;
    constexpr int KP = K + 8;
    __shared__ u16 A_lds[64 * KP];
    __shared__ u16 Wt_lds[64 * KP];
    __shared__ float red[128];
    __shared__ float affl[128];

    const int t = threadIdx.x;
    const int lane = t & 63;
    const int wv = t >> 6;
    const int l15 = lane & 15;
    const int lg = lane >> 4;

    for (int idx = t; idx < K * 16; idx += 256) {
        int k = idx >> 4, c4 = (idx & 15) * 4;
        float4 w4 = (k < K1) ? ld4(W1 + (size_t)k * 64 + c4)
                             : ld4(W2 + (size_t)(k - K1) * 64 + c4);
        Wt_lds[(c4 + 0) * KP + k] = f2b(w4.x);
        Wt_lds[(c4 + 1) * KP + k] = f2b(w4.y);
        Wt_lds[(c4 + 2) * KP + k] = f2b(w4.z);
        Wt_lds[(c4 + 3) * KP + k] = f2b(w4.w);
    }
    if (t < 128) red[t] = 0.f;
    if (AAFF && t < 64) {
        float2 p = bn_pair(aslot, ag, ab, t);
        affl[t] = p.x;
        affl[64 + t] = p.y;
    }

    float bias_c[4], be_c[4], rsc_c[4], rsh_c[4];
#pragma unroll
    for (int n = 0; n < 4; n++) {
        int ch = 16 * n + l15;
        bias_c[n] = bias[ch];
        be_c[n] = BE ? be[ch] : 0.f;
        if (RESID) {
            float2 p = bn_pair(rslot, rg, rb, ch);
            rsc_c[n] = p.x;
            rsh_c[n] = p.y;
        } else {
            rsc_c[n] = 0.f;
            rsh_c[n] = 0.f;
        }
    }

    for (int tile = blockIdx.x; tile < NTILES; tile += gridDim.x) {
        int nb = tile * 64;
        __syncthreads();
        if (A1BF) {
            const u16* A1b = (const u16*)A1v;
            for (int idx = t; idx < 64 * (K1 / 4); idx += 256) {
                int node = idx / (K1 / 4), kq = (idx % (K1 / 4)) * 4;
                int gn = nb + node;
                s4v v = {0, 0, 0, 0};
                if (gn < NN) {
                    v = *(const s4v*)(A1b + (size_t)gn * K1 + kq);
                    if (AAFF) {
#pragma unroll
                        for (int i = 0; i < 4; i++) {
                            float f = b2f((u16)v[i]) * affl[kq + i] + affl[64 + kq + i];
                            v[i] = (short)f2b(f);
                        }
                    }
                }
                *(s4v*)&A_lds[node * KP + kq] = v;
            }
        } else {
            const float* A1f = (const float*)A1v;
            for (int idx = t; idx < 64 * (K1 / 4); idx += 256) {
                int node = idx / (K1 / 4), kq = (idx % (K1 / 4)) * 4;
                int gn = nb + node;
                s4v v = {0, 0, 0, 0};
                if (gn < NN) {
                    float4 a = ld4(A1f + (size_t)gn * K1 + kq);
                    v[0] = (short)f2b(a.x); v[1] = (short)f2b(a.y);
                    v[2] = (short)f2b(a.z); v[3] = (short)f2b(a.w);
                }
                *(s4v*)&A_lds[node * KP + kq] = v;
            }
        }
        if (K2 > 0) {
            for (int idx = t; idx < 64 * (K2 / 4); idx += 256) {
                int node = idx / (K2 / 4), kq = (idx % (K2 / 4)) * 4;
                int gn = nb + node;
                s4v v = {0, 0, 0, 0};
                if (gn < NN) v = *(const s4v*)(A2 + (size_t)gn * K2 + kq);
                *(s4v*)&A_lds[node * KP + K1 + kq] = v;
            }
        }
        __syncthreads();

        f32x4 acc[4];
#pragma unroll
        for (int n = 0; n < 4; n++) acc[n] = (f32x4){0.f, 0.f, 0.f, 0.f};
        const int arow = 16 * wv + l15;
#pragma unroll
        for (int kk = 0; kk < K; kk += 32) {
            s4v alo = *(const s4v*)&A_lds[arow * KP + kk + lg * 4];
            s4v ahi = *(const s4v*)&A_lds[arow * KP + kk + lg * 4 + 16];
            bf16x8 a = __builtin_shufflevector(alo, ahi, 0, 1, 2, 3, 4, 5, 6, 7);
#pragma unroll
            for (int n = 0; n < 4; n++) {
                s4v wlo = *(const s4v*)&Wt_lds[(16 * n + l15) * KP + kk + lg * 4];
                s4v whi = *(const s4v*)&Wt_lds[(16 * n + l15) * KP + kk + lg * 4 + 16];
                bf16x8 b = __builtin_shufflevector(wlo, whi, 0, 1, 2, 3, 4, 5, 6, 7);
                acc[n] = __builtin_amdgcn_mfma_f32_16x16x32_bf16(a, b, acc[n], 0, 0, 0);
            }
        }

        float ss[4] = {0, 0, 0, 0}, sq2[4] = {0, 0, 0, 0};
#pragma unroll
        for (int r = 0; r < 4; r++) {
            int node = nb + 16 * wv + lg * 4 + r;
            if (node < NN) {
                float deg = BE ? (float)(row_ptr[node + 1] - row_ptr[node]) : 0.f;
                int nv = EMB ? nvi[node] : 0;
#pragma unroll
                for (int n = 0; n < 4; n++) {
                    int ch = 16 * n + l15;
                    float v = acc[n][r] + bias_c[n];
                    if (BE) v += deg * be_c[n];
                    if (EMB) v += emb[(size_t)nv * 64 + ch];
                    if (RESID) v += b2f(resid[(size_t)node * 64 + ch]) * rsc_c[n] + rsh_c[n];
                    v = fmaxf(v, 0.f);
                    Xb[(size_t)node * 64 + ch] = f2b(v);
                    ss[n] += v;
                    sq2[n] += v * v;
                }
            }
        }
#pragma unroll
        for (int n = 0; n < 4; n++) {
            float a = ss[n];
            a += __shfl_xor(a, 16);
            a += __shfl_xor(a, 32);
            float b = sq2[n];
            b += __shfl_xor(b, 16);
            b += __shfl_xor(b, 32);
            if (lg == 0) {
                atomicAdd(&red[16 * n + l15], a);
                atomicAdd(&red[64 + 16 * n + l15], b);
            }
        }
    }
    __syncthreads();
    if (t < 128) atomicAdd(&stats[t], red[t]);
}

// ---------------- message passing over packed bf16 h, inline BN ----------------
__global__ void kmsg_bf(const u64* __restrict__ h4, const int* __restrict__ row_ptr,
                        const int* __restrict__ src_s, const float* __restrict__ slot,
                        const float* __restrict__ g, const float* __restrict__ bb,
                        u64* __restrict__ agg) {
    int lane = threadIdx.x & 63;
    int wid = threadIdx.x >> 6;
    int w = lane & 15, sl = lane >> 4;
    float2 p0 = bn_pair(slot, g, bb, 4 * w);
    float2 p1 = bn_pair(slot, g, bb, 4 * w + 1);
    float2 p2 = bn_pair(slot, g, bb, 4 * w + 2);
    float2 p3 = bn_pair(slot, g, bb, 4 * w + 3);
    for (int n = blockIdx.x * 4 + wid; n < NN; n += gridDim.x * 4) {
        int e0 = row_ptr[n], e1 = row_ptr[n + 1];
        float a0 = 0.f, a1 = 0.f, a2 = 0.f, a3 = 0.f;
        int e = e0 + sl;
        for (; e + 12 < e1; e += 16) {
            int s0 = src_s[e], s1 = src_s[e + 4], s2 = src_s[e + 8], s3 = src_s[e + 12];
            u64 v0 = h4[(size_t)s0 * 16 + w];
            u64 v1 = h4[(size_t)s1 * 16 + w];
            u64 v2 = h4[(size_t)s2 * 16 + w];
            u64 v3 = h4[(size_t)s3 * 16 + w];
            u32 l0 = (u32)v0, h0 = (u32)(v0 >> 32);
            u32 l1 = (u32)v1, h1 = (u32)(v1 >> 32);
            u32 l2 = (u32)v2, h2w = (u32)(v2 >> 32);
            u32 l3 = (u32)v3, h3 = (u32)(v3 >> 32);
            a0 += (blo(l0) + blo(l1)) + (blo(l2) + blo(l3));
            a1 += (bhi(l0) + bhi(l1)) + (bhi(l2) + bhi(l3));
            a2 += (blo(h0) + blo(h1)) + (blo(h2w) + blo(h3));
            a3 += (bhi(h0) + bhi(h1)) + (bhi(h2w) + bhi(h3));
        }
        for (; e < e1; e += 4) {
            u64 v = h4[(size_t)src_s[e] * 16 + w];
            u32 l = (u32)v, h = (u32)(v >> 32);
            a0 += blo(l);
            a1 += bhi(l);
            a2 += blo(h);
            a3 += bhi(h);
        }
        a0 += __shfl_xor(a0, 16);
        a0 += __shfl_xor(a0, 32);
        a1 += __shfl_xor(a1, 16);
        a1 += __shfl_xor(a1, 32);
        a2 += __shfl_xor(a2, 16);
        a2 += __shfl_xor(a2, 32);
        a3 += __shfl_xor(a3, 16);
        a3 += __shfl_xor(a3, 32);
        if (sl == 0) {
            float deg = (float)(e1 - e0);
            u32 lo = pk2(p0.x * a0 + deg * p0.y, p1.x * a1 + deg * p1.y);
            u32 hi = pk2(p2.x * a2 + deg * p2.y, p3.x * a3 + deg * p3.y);
            agg[(size_t)n * 16 + w] = (u64)lo | ((u64)hi << 32);
        }
    }
}

// ---------------- segmented max readout, inline BN ----------------
__device__ __forceinline__ unsigned fenc(float f) {
    unsigned u = __float_as_uint(f);
    return (u >> 31) ? ~u : (u | 0x80000000u);
}
__device__ __forceinline__ float fdec(unsigned k) {
    return (k >> 31) ? __uint_as_float(k ^ 0x80000000u) : __uint_as_float(~k);
}

__global__ void kinitpk(unsigned* __restrict__ pk) {
    int i = blockIdx.x * blockDim.x + threadIdx.x;
    if (i < GG * DD) pk[i] = 0x007FFFFFu;
}

__global__ void kread(const u16* __restrict__ h2, const int* __restrict__ gidx,
                      const float* __restrict__ slot, const float* __restrict__ g,
                      const float* __restrict__ bb, unsigned* __restrict__ pk) {
    int lane = threadIdx.x & 63;
    int wid = threadIdx.x >> 6;
    float2 p = bn_pair(slot, g, bb, lane);
    float sc = p.x, sh = p.y;
    int gw = blockIdx.x * 4 + wid;
    int nw = gridDim.x * 4;
    int chunk = (NN + nw - 1) / nw;
    int lo = gw * chunk, hi = min(lo + chunk, NN);
    if (lo >= hi) return;
    int cur = gidx[lo];
    float acc = -INFINITY;
    for (int n = lo; n < hi; n++) {
        int gg = gidx[n];
        if (gg != cur) {
            atomicMax(&pk[cur * DD + lane], fenc(acc));
            cur = gg;
            acc = -INFINITY;
        }
        acc = fmaxf(acc, b2f(h2[(size_t)n * 64 + lane]) * sc + sh);
    }
    atomicMax(&pk[cur * DD + lane], fenc(acc));
}

__global__ void kout(const unsigned* __restrict__ pk, const float* __restrict__ W,
                     const float* __restrict__ b, float* __restrict__ out) {
    int t = blockIdx.x * blockDim.x + threadIdx.x;
    int g = t >> 6, d = t & 63;
    float acc = b[d];
    for (int k = 0; k < DD; k++) {
        float p = fdec(pk[g * DD + k]);
        acc += p * W[k * DD + d];
    }
    out[t] = fmaxf(acc, 0.f);
}

extern "C" void kernel_launch(void* const* d_in, const int* in_sizes, int n_in,
                              void* d_out, int out_size, void* d_ws, size_t ws_size,
                              hipStream_t stream) {
    const float* node_feat = (const float*)d_in[0];
    const float* edge_feat = (const float*)d_in[1];
    const float* w_n2l_W = (const float*)d_in[2];
    const float* w_n2l_b = (const float*)d_in[3];
    const float* nve = (const float*)d_in[4];
    const float* w_e2l_W = (const float*)d_in[5];
    const float* w_e2l_b = (const float*)d_in[6];
    const float* conv_W = (const float*)d_in[7];
    const float* conv_b = (const float*)d_in[8];
    const float* l2_W = (const float*)d_in[9];
    const float* l2_b = (const float*)d_in[10];
    const float* msg_g = (const float*)d_in[11];
    const float* msg_b = (const float*)d_in[12];
    const float* hid_g = (const float*)d_in[13];
    const float* hid_b = (const float*)d_in[14];
    const float* out_W = (const float*)d_in[15];
    const float* out_b = (const float*)d_in[16];
    const int* edge_from = (const int*)d_in[17];
    const int* edge_to = (const int*)d_in[18];
    const int* g_idx = (const int*)d_in[19];
    const int* nvi = (const int*)d_in[20];
    float* out = (float*)d_out;

    char* ws = (char*)d_ws;
    size_t off = 0;
    auto alloc = [&](size_t bytes) -> void* {
        void* p = ws + off;
        off += (bytes + 255) / 256 * 256;
        return p;
    };
    int* row_ptr = (int*)alloc((size_t)(NN + 1) * 4);
    int* src_s = (int*)alloc((size_t)EE * 4);
    int* perm = (int*)alloc((size_t)EE * 4);
    int* tmpw = (int*)alloc((size_t)EE * 4);
    uint4* tmp_ef = (uint4*)alloc((size_t)EE * 64);
    u16* pooled_ef = (u16*)alloc((size_t)NN * EF * 2);
    u16* h2a = (u16*)alloc((size_t)NN * DD * 2);
    u16* h2b = (u16*)alloc((size_t)NN * DD * 2);
    u16* agg_bf = (u16*)alloc((size_t)NN * DD * 2);
    u16* mb_bf = (u16*)alloc((size_t)NN * DD * 2);
    float* stats = (float*)alloc(1024 * 4);  // 8 slots x 128 raw sums
    unsigned* pk = (unsigned*)alloc((size_t)GG * DD * 4);
    int* bhist = (int*)alloc((size_t)NBKT * 4);
    int* bbase = (int*)alloc((size_t)(NBKT + 1) * 4);
    int* gcur = (int*)alloc((size_t)NBKT * 4);
    (void)ws_size; (void)n_in; (void)in_sizes; (void)out_size;

    hipMemsetAsync(bhist, 0, (size_t)NBKT * 4, stream);
    hipMemsetAsync(stats, 0, 1024 * 4, stream);
    kinitpk<<<16, 256, 0, stream>>>(pk);

    k1b<<<256, 256, 0, stream>>>(edge_to, bhist);
    k1c<<<1, 512, 0, stream>>>(bhist, bbase, gcur);
    k1d<<<512, 256, 0, stream>>>(edge_to, edge_from, edge_feat, gcur, tmpw, tmp_ef);
    kp2<<<NBKT, 256, 0, stream>>>(tmpw, tmp_ef, bbase, row_ptr, src_s, perm, pooled_ef);

    const int GB = 782;
    const float* S = stats;  // slot i at stats + i*128

    // h0 -> h2a, stats slot 0
    kgemm_mfma<NF, EF, false, false, true, true, false>
        <<<GB, 256, 0, stream>>>(node_feat, pooled_ef, w_n2l_W, w_e2l_W,
                                 w_n2l_b, w_e2l_b, row_ptr, nve, nvi, nullptr,
                                 nullptr, nullptr, nullptr, nullptr, nullptr, nullptr,
                                 h2a, stats + 0 * 128);

    u16* hcur = h2a;
    u16* hnext = h2b;
    for (int lv = 0; lv < LVL; lv++) {
        // gather + msg-BN(slot lv) -> agg
        kmsg_bf<<<4096, 256, 0, stream>>>((const u64*)hcur, row_ptr, src_s,
                                          S + lv * 128, msg_g + lv * 64, msg_b + lv * 64,
                                          (u64*)agg_bf);
        // merged = relu(agg@cW + pooled@We + cb + deg*be) -> mb, stats slot 4+lv
        kgemm_mfma<DD, EF, true, false, false, true, false>
            <<<GB, 256, 0, stream>>>(agg_bf, pooled_ef, conv_W + lv * DD * DD,
                                     w_e2l_W + (size_t)(lv + 1) * EF * DD,
                                     conv_b + lv * DD,
                                     w_e2l_b + (size_t)(lv + 1) * DD, row_ptr,
                                     nullptr, nullptr, nullptr, nullptr, nullptr,
                                     nullptr, nullptr, nullptr, nullptr,
                                     mb_bf, stats + (4 + lv) * 128);
        // hnext = relu(hidBN(mb)@l2W + l2b + msgBN(hcur)), stats slot lv+1
        kgemm_mfma<DD, 0, true, true, false, false, true>
            <<<GB, 256, 0, stream>>>(mb_bf, nullptr, l2_W + lv * DD * DD, nullptr,
                                     l2_b + lv * DD, nullptr, row_ptr, nullptr,
                                     nullptr, hcur,
                                     S + lv * 128, msg_g + lv * 64, msg_b + lv * 64,
                                     S + (4 + lv) * 128, hid_g + lv * 64, hid_b + lv * 64,
                                     hnext, stats + (lv + 1) * 128);
        u16* tsw = hcur; hcur = hnext; hnext = tsw;
    }

    kread<<<1024, 256, 0, stream>>>(hcur, g_idx, S + LVL * 128, msg_g + LVL * 64,
                                    msg_b + LVL * 64, pk);
    kout<<<GG, 64, 0, stream>>>(pk, out_W, out_b, out);
}

// Round 10
// 610.800 us; speedup vs baseline: 1.0255x; 1.0255x over previous
//
#include <hip/hip_runtime.h>
#include <math.h>

#define NN 100000
#define EE 1600000
#define GG 64
#define DD 64
#define NF 128
#define EF 32
#define LVL 3
#define EPSBN 1e-5f
#define NTILES ((NN + 63) / 64)
#define NBKT 391  // ceil(NN / 256)

typedef unsigned short u16;
typedef unsigned int u32;
typedef unsigned long long u64;
typedef short s4v __attribute__((ext_vector_type(4)));
typedef short bf16x8 __attribute__((ext_vector_type(8)));
typedef float f32x4 __attribute__((ext_vector_type(4)));

__device__ __forceinline__ float4 ld4(const float* p) { return *(const float4*)p; }
__device__ __forceinline__ u16 f2b(float f) {
    u32 u = __float_as_uint(f);
    return (u16)((u + 0x7FFFu + ((u >> 16) & 1u)) >> 16);
}
__device__ __forceinline__ u32 pk2(float x, float y) {
    return (u32)f2b(x) | ((u32)f2b(y) << 16);
}
__device__ __forceinline__ float b2f(u16 u) { return __uint_as_float(((u32)u) << 16); }
__device__ __forceinline__ float blo(u32 u) { return __uint_as_float(u << 16); }
__device__ __forceinline__ float bhi(u32 u) { return __uint_as_float(u & 0xFFFF0000u); }

// BN scale/shift from raw sums slot (training-mode biased stats)
__device__ __forceinline__ float2 bn_pair(const float* __restrict__ slot,
                                          const float* __restrict__ g,
                                          const float* __restrict__ b, int ch) {
    float mean = slot[ch] * (1.0f / NN);
    float var = slot[64 + ch] * (1.0f / NN) - mean * mean;
    float sc = g[ch] * rsqrtf(fmaxf(var, 0.f) + EPSBN);
    return make_float2(sc, b[ch] - mean * sc);
}

// ---------------- CSR build: two-level bucket sort ----------------
__global__ void k1b(const int* __restrict__ to, int* __restrict__ bhist) {
    __shared__ int h[NBKT];
    for (int i = threadIdx.x; i < NBKT; i += 256) h[i] = 0;
    __syncthreads();
    for (int e = blockIdx.x * 256 + threadIdx.x; e < EE; e += 256 * gridDim.x)
        atomicAdd(&h[to[e] >> 8], 1);
    __syncthreads();
    for (int i = threadIdx.x; i < NBKT; i += 256)
        if (h[i]) atomicAdd(&bhist[i], h[i]);
}

__global__ void k1c(const int* __restrict__ bhist, int* __restrict__ bbase,
                    int* __restrict__ gcur) {
    __shared__ int s[512];
    int t = threadIdx.x;
    s[t] = (t < NBKT) ? bhist[t] : 0;
    __syncthreads();
    for (int off = 1; off < 512; off <<= 1) {
        int v = (t >= off) ? s[t - off] : 0;
        __syncthreads();
        s[t] += v;
        __syncthreads();
    }
    if (t < NBKT) {
        int base = t ? s[t - 1] : 0;
        bbase[t] = base;
        gcur[t] = base;
    }
    if (t == NBKT - 1) bbase[NBKT] = s[t];
}

// partition edges into bucket-contiguous tmp: word0 = from | (rel_to<<17), word1 = e
__global__ void k1d(const int* __restrict__ to, const int* __restrict__ from,
                    int* __restrict__ gcur, int2* __restrict__ tmp) {
    __shared__ int h[NBKT];
    __shared__ int cur[NBKT];
    for (int i = threadIdx.x; i < NBKT; i += 256) h[i] = 0;
    __syncthreads();
    for (int e = blockIdx.x * 256 + threadIdx.x; e < EE; e += 256 * gridDim.x)
        atomicAdd(&h[to[e] >> 8], 1);
    __syncthreads();
    for (int i = threadIdx.x; i < NBKT; i += 256)
        cur[i] = h[i] ? atomicAdd(&gcur[i], h[i]) : 0;
    __syncthreads();
    for (int e = blockIdx.x * 256 + threadIdx.x; e < EE; e += 256 * gridDim.x) {
        int tt = to[e];
        int b = tt >> 8;
        int pos = atomicAdd(&cur[b], 1);
        tmp[pos] = make_int2(from[e] | ((tt & 255) << 17), e);
    }
}

// per-bucket: LDS histogram+scan -> row_ptr; scatter split arrays src_s / eid_s
__global__ void kp2(const int2* __restrict__ tmp, const int* __restrict__ bbase,
                    int* __restrict__ row_ptr, int* __restrict__ src_s,
                    int* __restrict__ eid_s) {
    __shared__ int s[256];
    __shared__ int cur[256];
    int b = blockIdx.x, t = threadIdx.x;
    int e0 = bbase[b], e1 = bbase[b + 1];
    s[t] = 0;
    __syncthreads();
    for (int e = e0 + t; e < e1; e += 256) atomicAdd(&s[(tmp[e].x >> 17) & 255], 1);
    __syncthreads();
    int v = s[t];
    for (int off = 1; off < 256; off <<= 1) {
        int u = (t >= off) ? s[t - off] : 0;
        __syncthreads();
        s[t] += u;
        __syncthreads();
    }
    int excl = e0 + s[t] - v;
    cur[t] = excl;
    int n = b * 256 + t;
    if (n < NN) row_ptr[n] = excl;
    if (b == NBKT - 1 && t == 0) row_ptr[NN] = e1;
    __syncthreads();
    for (int e = e0 + t; e < e1; e += 256) {
        int2 w = tmp[e];
        int pos = atomicAdd(&cur[(w.x >> 17) & 255], 1);
        src_s[pos] = w.x & 0x1FFFF;
        eid_s[pos] = w.y;
    }
}

// ---------------- edge-feature pooling -> packed bf16 ----------------
// wave per node: 4 edge-slots x 16 lanes x float2 (8B); 16 rows in flight
__global__ void kpool(const float* __restrict__ ef, const int* __restrict__ row_ptr,
                      const int* __restrict__ eid_s, u16* __restrict__ pooled) {
    int lane = threadIdx.x & 63;
    int wid = threadIdx.x >> 6;
    int w = lane & 15, slot = lane >> 4;
    for (int n = blockIdx.x * 4 + wid; n < NN; n += gridDim.x * 4) {
        int e0 = row_ptr[n], e1 = row_ptr[n + 1];
        float ax = 0.f, ay = 0.f;
        int e = e0 + slot;
        for (; e + 12 < e1; e += 16) {
            int i0 = eid_s[e], i1 = eid_s[e + 4], i2 = eid_s[e + 8], i3 = eid_s[e + 12];
            float2 v0 = *(const float2*)(ef + (size_t)i0 * EF + 2 * w);
            float2 v1 = *(const float2*)(ef + (size_t)i1 * EF + 2 * w);
            float2 v2 = *(const float2*)(ef + (size_t)i2 * EF + 2 * w);
            float2 v3 = *(const float2*)(ef + (size_t)i3 * EF + 2 * w);
            ax += (v0.x + v1.x) + (v2.x + v3.x);
            ay += (v0.y + v1.y) + (v2.y + v3.y);
        }
        for (; e < e1; e += 4) {
            float2 v = *(const float2*)(ef + (size_t)eid_s[e] * EF + 2 * w);
            ax += v.x;
            ay += v.y;
        }
        ax += __shfl_xor(ax, 16);
        ax += __shfl_xor(ax, 32);
        ay += __shfl_xor(ay, 16);
        ay += __shfl_xor(ay, 32);
        if (slot == 0) *(u32*)&pooled[(size_t)n * EF + 2 * w] = pk2(ax, ay);
    }
}

// ---------------- MFMA bf16 fused GEMM (h0 / merge / l2), inline BN ----------------
template <int K1, int K2, bool A1BF, bool AAFF, bool EMB, bool BE, bool RESID>
__global__ __launch_bounds__(256) void kgemm_mfma(
    const void* __restrict__ A1v, const u16* __restrict__ A2,
    const float* __restrict__ W1, const float* __restrict__ W2,
    const float* __restrict__ bias, const float* __restrict__ be,
    const int* __restrict__ row_ptr, const float* __restrict__ emb,
    const int* __restrict__ nvi, const u16* __restrict__ resid,
    const float* __restrict__ rslot, const float* __restrict__ rg,
    const float* __restrict__ rb, const float* __restrict__ aslot,
    const float* __restrict__ ag, const float* __restrict__ ab,
    u16* __restrict__ Xb, float* __restrict__ stats) {
    constexpr int K = K1 + K2;
    constexpr int KP = K + 8;
    __shared__ u16 A_lds[64 * KP];
    __shared__ u16 Wt_lds[64 * KP];
    __shared__ float red[128];
    __shared__ float affl[128];

    const int t = threadIdx.x;
    const int lane = t & 63;
    const int wv = t >> 6;
    const int l15 = lane & 15;
    const int lg = lane >> 4;

    for (int idx = t; idx < K * 16; idx += 256) {
        int k = idx >> 4, c4 = (idx & 15) * 4;
        float4 w4 = (k < K1) ? ld4(W1 + (size_t)k * 64 + c4)
                             : ld4(W2 + (size_t)(k - K1) * 64 + c4);
        Wt_lds[(c4 + 0) * KP + k] = f2b(w4.x);
        Wt_lds[(c4 + 1) * KP + k] = f2b(w4.y);
        Wt_lds[(c4 + 2) * KP + k] = f2b(w4.z);
        Wt_lds[(c4 + 3) * KP + k] = f2b(w4.w);
    }
    if (t < 128) red[t] = 0.f;
    if (AAFF && t < 64) {
        float2 p = bn_pair(aslot, ag, ab, t);
        affl[t] = p.x;
        affl[64 + t] = p.y;
    }

    float bias_c[4], be_c[4], rsc_c[4], rsh_c[4];
#pragma unroll
    for (int n = 0; n < 4; n++) {
        int ch = 16 * n + l15;
        bias_c[n] = bias[ch];
        be_c[n] = BE ? be[ch] : 0.f;
        if (RESID) {
            float2 p = bn_pair(rslot, rg, rb, ch);
            rsc_c[n] = p.x;
            rsh_c[n] = p.y;
        } else {
            rsc_c[n] = 0.f;
            rsh_c[n] = 0.f;
        }
    }

    for (int tile = blockIdx.x; tile < NTILES; tile += gridDim.x) {
        int nb = tile * 64;
        __syncthreads();
        if (A1BF) {
            const u16* A1b = (const u16*)A1v;
            for (int idx = t; idx < 64 * (K1 / 4); idx += 256) {
                int node = idx / (K1 / 4), kq = (idx % (K1 / 4)) * 4;
                int gn = nb + node;
                s4v v = {0, 0, 0, 0};
                if (gn < NN) {
                    v = *(const s4v*)(A1b + (size_t)gn * K1 + kq);
                    if (AAFF) {
#pragma unroll
                        for (int i = 0; i < 4; i++) {
                            float f = b2f((u16)v[i]) * affl[kq + i] + affl[64 + kq + i];
                            v[i] = (short)f2b(f);
                        }
                    }
                }
                *(s4v*)&A_lds[node * KP + kq] = v;
            }
        } else {
            const float* A1f = (const float*)A1v;
            for (int idx = t; idx < 64 * (K1 / 4); idx += 256) {
                int node = idx / (K1 / 4), kq = (idx % (K1 / 4)) * 4;
                int gn = nb + node;
                s4v v = {0, 0, 0, 0};
                if (gn < NN) {
                    float4 a = ld4(A1f + (size_t)gn * K1 + kq);
                    v[0] = (short)f2b(a.x); v[1] = (short)f2b(a.y);
                    v[2] = (short)f2b(a.z); v[3] = (short)f2b(a.w);
                }
                *(s4v*)&A_lds[node * KP + kq] = v;
            }
        }
        if (K2 > 0) {
            for (int idx = t; idx < 64 * (K2 / 4); idx += 256) {
                int node = idx / (K2 / 4), kq = (idx % (K2 / 4)) * 4;
                int gn = nb + node;
                s4v v = {0, 0, 0, 0};
                if (gn < NN) v = *(const s4v*)(A2 + (size_t)gn * K2 + kq);
                *(s4v*)&A_lds[node * KP + K1 + kq] = v;
            }
        }
        __syncthreads();

        f32x4 acc[4];
#pragma unroll
        for (int n = 0; n < 4; n++) acc[n] = (f32x4){0.f, 0.f, 0.f, 0.f};
        const int arow = 16 * wv + l15;
#pragma unroll
        for (int kk = 0; kk < K; kk += 32) {
            s4v alo = *(const s4v*)&A_lds[arow * KP + kk + lg * 4];
            s4v ahi = *(const s4v*)&A_lds[arow * KP + kk + lg * 4 + 16];
            bf16x8 a = __builtin_shufflevector(alo, ahi, 0, 1, 2, 3, 4, 5, 6, 7);
#pragma unroll
            for (int n = 0; n < 4; n++) {
                s4v wlo = *(const s4v*)&Wt_lds[(16 * n + l15) * KP + kk + lg * 4];
                s4v whi = *(const s4v*)&Wt_lds[(16 * n + l15) * KP + kk + lg * 4 + 16];
                bf16x8 b = __builtin_shufflevector(wlo, whi, 0, 1, 2, 3, 4, 5, 6, 7);
                acc[n] = __builtin_amdgcn_mfma_f32_16x16x32_bf16(a, b, acc[n], 0, 0, 0);
            }
        }

        float ss[4] = {0, 0, 0, 0}, sq2[4] = {0, 0, 0, 0};
#pragma unroll
        for (int r = 0; r < 4; r++) {
            int node = nb + 16 * wv + lg * 4 + r;
            if (node < NN) {
                float deg = BE ? (float)(row_ptr[node + 1] - row_ptr[node]) : 0.f;
                int nv = EMB ? nvi[node] : 0;
#pragma unroll
                for (int n = 0; n < 4; n++) {
                    int ch = 16 * n + l15;
                    float v = acc[n][r] + bias_c[n];
                    if (BE) v += deg * be_c[n];
                    if (EMB) v += emb[(size_t)nv * 64 + ch];
                    if (RESID) v += b2f(resid[(size_t)node * 64 + ch]) * rsc_c[n] + rsh_c[n];
                    v = fmaxf(v, 0.f);
                    Xb[(size_t)node * 64 + ch] = f2b(v);
                    ss[n] += v;
                    sq2[n] += v * v;
                }
            }
        }
#pragma unroll
        for (int n = 0; n < 4; n++) {
            float a = ss[n];
            a += __shfl_xor(a, 16);
            a += __shfl_xor(a, 32);
            float b = sq2[n];
            b += __shfl_xor(b, 16);
            b += __shfl_xor(b, 32);
            if (lg == 0) {
                atomicAdd(&red[16 * n + l15], a);
                atomicAdd(&red[64 + 16 * n + l15], b);
            }
        }
    }
    __syncthreads();
    if (t < 128) atomicAdd(&stats[t], red[t]);
}

// ---------------- message passing over packed bf16 h, inline BN ----------------
__global__ void kmsg_bf(const u64* __restrict__ h4, const int* __restrict__ row_ptr,
                        const int* __restrict__ src_s, const float* __restrict__ slot,
                        const float* __restrict__ g, const float* __restrict__ bb,
                        u64* __restrict__ agg) {
    int lane = threadIdx.x & 63;
    int wid = threadIdx.x >> 6;
    int w = lane & 15, sl = lane >> 4;
    float2 p0 = bn_pair(slot, g, bb, 4 * w);
    float2 p1 = bn_pair(slot, g, bb, 4 * w + 1);
    float2 p2 = bn_pair(slot, g, bb, 4 * w + 2);
    float2 p3 = bn_pair(slot, g, bb, 4 * w + 3);
    for (int n = blockIdx.x * 4 + wid; n < NN; n += gridDim.x * 4) {
        int e0 = row_ptr[n], e1 = row_ptr[n + 1];
        float a0 = 0.f, a1 = 0.f, a2 = 0.f, a3 = 0.f;
        int e = e0 + sl;
        for (; e + 12 < e1; e += 16) {
            int s0 = src_s[e], s1 = src_s[e + 4], s2 = src_s[e + 8], s3 = src_s[e + 12];
            u64 v0 = h4[(size_t)s0 * 16 + w];
            u64 v1 = h4[(size_t)s1 * 16 + w];
            u64 v2 = h4[(size_t)s2 * 16 + w];
            u64 v3 = h4[(size_t)s3 * 16 + w];
            u32 l0 = (u32)v0, h0 = (u32)(v0 >> 32);
            u32 l1 = (u32)v1, h1 = (u32)(v1 >> 32);
            u32 l2 = (u32)v2, h2w = (u32)(v2 >> 32);
            u32 l3 = (u32)v3, h3 = (u32)(v3 >> 32);
            a0 += (blo(l0) + blo(l1)) + (blo(l2) + blo(l3));
            a1 += (bhi(l0) + bhi(l1)) + (bhi(l2) + bhi(l3));
            a2 += (blo(h0) + blo(h1)) + (blo(h2w) + blo(h3));
            a3 += (bhi(h0) + bhi(h1)) + (bhi(h2w) + bhi(h3));
        }
        for (; e < e1; e += 4) {
            u64 v = h4[(size_t)src_s[e] * 16 + w];
            u32 l = (u32)v, h = (u32)(v >> 32);
            a0 += blo(l);
            a1 += bhi(l);
            a2 += blo(h);
            a3 += bhi(h);
        }
        a0 += __shfl_xor(a0, 16);
        a0 += __shfl_xor(a0, 32);
        a1 += __shfl_xor(a1, 16);
        a1 += __shfl_xor(a1, 32);
        a2 += __shfl_xor(a2, 16);
        a2 += __shfl_xor(a2, 32);
        a3 += __shfl_xor(a3, 16);
        a3 += __shfl_xor(a3, 32);
        if (sl == 0) {
            float deg = (float)(e1 - e0);
            u32 lo = pk2(p0.x * a0 + deg * p0.y, p1.x * a1 + deg * p1.y);
            u32 hi = pk2(p2.x * a2 + deg * p2.y, p3.x * a3 + deg * p3.y);
            agg[(size_t)n * 16 + w] = (u64)lo | ((u64)hi << 32);
        }
    }
}

// ---------------- segmented max readout, inline BN, 4-slot u64 ----------------
__device__ __forceinline__ unsigned fenc(float f) {
    unsigned u = __float_as_uint(f);
    return (u >> 31) ? ~u : (u | 0x80000000u);
}
__device__ __forceinline__ float fdec(unsigned k) {
    return (k >> 31) ? __uint_as_float(k ^ 0x80000000u) : __uint_as_float(~k);
}

__global__ void kinitpk(unsigned* __restrict__ pk) {
    int i = blockIdx.x * blockDim.x + threadIdx.x;
    if (i < GG * DD) pk[i] = 0x007FFFFFu;  // fenc(-inf)
}

__global__ void kread(const u64* __restrict__ h4, const int* __restrict__ gidx,
                      const float* __restrict__ slot, const float* __restrict__ g,
                      const float* __restrict__ bb, unsigned* __restrict__ pk) {
    int lane = threadIdx.x & 63;
    int wid = threadIdx.x >> 6;
    int w = lane & 15, sl = lane >> 4;  // channels 4w..4w+3, node slot sl
    float2 p0 = bn_pair(slot, g, bb, 4 * w);
    float2 p1 = bn_pair(slot, g, bb, 4 * w + 1);
    float2 p2 = bn_pair(slot, g, bb, 4 * w + 2);
    float2 p3 = bn_pair(slot, g, bb, 4 * w + 3);
    int gw = blockIdx.x * 4 + wid;
    int nw = gridDim.x * 4;
    int chunk = (NN + nw - 1) / nw;
    int lo = gw * chunk, hi = min(lo + chunk, NN);
    int n = lo + sl;
    if (n >= hi) return;
    int cur = gidx[n];
    float m0 = -INFINITY, m1 = -INFINITY, m2 = -INFINITY, m3 = -INFINITY;
    for (; n < hi; n += 4) {
        int gg = gidx[n];
        if (gg != cur) {
            atomicMax(&pk[cur * DD + 4 * w + 0], fenc(m0));
            atomicMax(&pk[cur * DD + 4 * w + 1], fenc(m1));
            atomicMax(&pk[cur * DD + 4 * w + 2], fenc(m2));
            atomicMax(&pk[cur * DD + 4 * w + 3], fenc(m3));
            cur = gg;
            m0 = m1 = m2 = m3 = -INFINITY;
        }
        u64 v = h4[(size_t)n * 16 + w];
        u32 l = (u32)v, h = (u32)(v >> 32);
        m0 = fmaxf(m0, blo(l) * p0.x + p0.y);
        m1 = fmaxf(m1, bhi(l) * p1.x + p1.y);
        m2 = fmaxf(m2, blo(h) * p2.x + p2.y);
        m3 = fmaxf(m3, bhi(h) * p3.x + p3.y);
    }
    atomicMax(&pk[cur * DD + 4 * w + 0], fenc(m0));
    atomicMax(&pk[cur * DD + 4 * w + 1], fenc(m1));
    atomicMax(&pk[cur * DD + 4 * w + 2], fenc(m2));
    atomicMax(&pk[cur * DD + 4 * w + 3], fenc(m3));
}

__global__ void kout(const unsigned* __restrict__ pk, const float* __restrict__ W,
                     const float* __restrict__ b, float* __restrict__ out) {
    int t = blockIdx.x * blockDim.x + threadIdx.x;
    int g = t >> 6, d = t & 63;
    float acc = b[d];
    for (int k = 0; k < DD; k++) {
        float p = fdec(pk[g * DD + k]);
        acc += p * W[k * DD + d];
    }
    out[t] = fmaxf(acc, 0.f);
}

extern "C" void kernel_launch(void* const* d_in, const int* in_sizes, int n_in,
                              void* d_out, int out_size, void* d_ws, size_t ws_size,
                              hipStream_t stream) {
    const float* node_feat = (const float*)d_in[0];
    const float* edge_feat = (const float*)d_in[1];
    const float* w_n2l_W = (const float*)d_in[2];
    const float* w_n2l_b = (const float*)d_in[3];
    const float* nve = (const float*)d_in[4];
    const float* w_e2l_W = (const float*)d_in[5];
    const float* w_e2l_b = (const float*)d_in[6];
    const float* conv_W = (const float*)d_in[7];
    const float* conv_b = (const float*)d_in[8];
    const float* l2_W = (const float*)d_in[9];
    const float* l2_b = (const float*)d_in[10];
    const float* msg_g = (const float*)d_in[11];
    const float* msg_b = (const float*)d_in[12];
    const float* hid_g = (const float*)d_in[13];
    const float* hid_b = (const float*)d_in[14];
    const float* out_W = (const float*)d_in[15];
    const float* out_b = (const float*)d_in[16];
    const int* edge_from = (const int*)d_in[17];
    const int* edge_to = (const int*)d_in[18];
    const int* g_idx = (const int*)d_in[19];
    const int* nvi = (const int*)d_in[20];
    float* out = (float*)d_out;

    char* ws = (char*)d_ws;
    size_t off = 0;
    auto alloc = [&](size_t bytes) -> void* {
        void* p = ws + off;
        off += (bytes + 255) / 256 * 256;
        return p;
    };
    int* row_ptr = (int*)alloc((size_t)(NN + 1) * 4);
    int* src_s = (int*)alloc((size_t)EE * 4);
    int* eid_s = (int*)alloc((size_t)EE * 4);
    int2* tmp = (int2*)alloc((size_t)EE * 8);
    u16* pooled_ef = (u16*)alloc((size_t)NN * EF * 2);
    u16* h2a = (u16*)alloc((size_t)NN * DD * 2);
    u16* h2b = (u16*)alloc((size_t)NN * DD * 2);
    u16* agg_bf = (u16*)alloc((size_t)NN * DD * 2);
    u16* mb_bf = (u16*)alloc((size_t)NN * DD * 2);
    float* stats = (float*)alloc(1024 * 4);  // 8 slots x 128 raw sums
    unsigned* pk = (unsigned*)alloc((size_t)GG * DD * 4);
    int* bhist = (int*)alloc((size_t)NBKT * 4);
    int* bbase = (int*)alloc((size_t)(NBKT + 1) * 4);
    int* gcur = (int*)alloc((size_t)NBKT * 4);
    (void)ws_size; (void)n_in; (void)in_sizes; (void)out_size;

    hipMemsetAsync(bhist, 0, (size_t)NBKT * 4, stream);
    hipMemsetAsync(stats, 0, 1024 * 4, stream);
    kinitpk<<<16, 256, 0, stream>>>(pk);

    k1b<<<256, 256, 0, stream>>>(edge_to, bhist);
    k1c<<<1, 512, 0, stream>>>(bhist, bbase, gcur);
    k1d<<<256, 256, 0, stream>>>(edge_to, edge_from, gcur, tmp);
    kp2<<<NBKT, 256, 0, stream>>>(tmp, bbase, row_ptr, src_s, eid_s);
    kpool<<<4096, 256, 0, stream>>>(edge_feat, row_ptr, eid_s, pooled_ef);

    const int GB = 782;
    const float* S = stats;  // slot i at stats + i*128

    // h0 -> h2a, stats slot 0
    kgemm_mfma<NF, EF, false, false, true, true, false>
        <<<GB, 256, 0, stream>>>(node_feat, pooled_ef, w_n2l_W, w_e2l_W,
                                 w_n2l_b, w_e2l_b, row_ptr, nve, nvi, nullptr,
                                 nullptr, nullptr, nullptr, nullptr, nullptr, nullptr,
                                 h2a, stats + 0 * 128);

    u16* hcur = h2a;
    u16* hnext = h2b;
    for (int lv = 0; lv < LVL; lv++) {
        // gather + msg-BN(slot lv) -> agg
        kmsg_bf<<<4096, 256, 0, stream>>>((const u64*)hcur, row_ptr, src_s,
                                          S + lv * 128, msg_g + lv * 64, msg_b + lv * 64,
                                          (u64*)agg_bf);
        // merged = relu(agg@cW + pooled@We + cb + deg*be) -> mb, stats slot 4+lv
        kgemm_mfma<DD, EF, true, false, false, true, false>
            <<<GB, 256, 0, stream>>>(agg_bf, pooled_ef, conv_W + lv * DD * DD,
                                     w_e2l_W + (size_t)(lv + 1) * EF * DD,
                                     conv_b + lv * DD,
                                     w_e2l_b + (size_t)(lv + 1) * DD, row_ptr,
                                     nullptr, nullptr, nullptr, nullptr, nullptr,
                                     nullptr, nullptr, nullptr, nullptr,
                                     mb_bf, stats + (4 + lv) * 128);
        // hnext = relu(hidBN(mb)@l2W + l2b + msgBN(hcur)), stats slot lv+1
        kgemm_mfma<DD, 0, true, true, false, false, true>
            <<<GB, 256, 0, stream>>>(mb_bf, nullptr, l2_W + lv * DD * DD, nullptr,
                                     l2_b + lv * DD, nullptr, row_ptr, nullptr,
                                     nullptr, hcur,
                                     S + lv * 128, msg_g + lv * 64, msg_b + lv * 64,
                                     S + (4 + lv) * 128, hid_g + lv * 64, hid_b + lv * 64,
                                     hnext, stats + (lv + 1) * 128);
        u16* tsw = hcur; hcur = hnext; hnext = tsw;
    }

    kread<<<1024, 256, 0, stream>>>((const u64*)hcur, g_idx, S + LVL * 128,
                                    msg_g + LVL * 64, msg_b + LVL * 64, pk);
    kout<<<GG, 64, 0, stream>>>(pk, out_W, out_b, out);
}